// Round 6
// baseline (258.821 us; speedup 1.0000x reference)
//
#include <hip/hip_runtime.h>

// filtfilt (order-2 biquad, odd-ext pad=9) over 1024 rows x 32768 fp32.
//
// R9 = R8 (swizzled all-b128 LDS staging, lane-independent fwd/bwd compute)
// + persistent pipelined waves. R8 was still latency-bound (kernel ~77us,
// nothing saturated: one-shot waves serialize load->vmcnt->LDS->recur->out
// with no in-wave overlap). Here each wave owns 8 consecutive segments of a
// row and prefetches tile i+1's 5 global float4 loads into registers right
// after tile i's stage+patch, hiding HBM latency (~900cy) under tile i's
// window-read + 80-step recurrence + copy-out (~1000cy). Per-wave preamble
// (coeff loads, rcp, address setup) amortizes 8x; all LDS/SWZ offsets are
// loop-invariant. 4096 waves = one resident generation (16 waves/CU at
// launch_bounds(256,4); VGPR est ~105 < 128 cap).
// Barrier-free: intra-wave LDS program order + compile-time fences at the
// cross-lane seams. Warmup 16/16 (err 0.577^16 ~ 1.5e-4); edges exact.

#define N_COLS 32768
#define PAD 9
#define LTOT  (N_COLS + 2 * PAD)   // 32786
#define WF 16
#define WB 16
#define C  16                      // outputs per lane
#define LANES 64
#define P   (C * LANES)            // 1024 outputs per tile
#define NSEG (N_COLS / P)          // 32
#define WIN (WF + C + WB)          // 48 floats per lane
#define SLICE (WF + P + WB)        // 1056 floats = 128B-multiple
#define NV4 (SLICE / 4)            // 264 float4 per slice
#define NITER 8                    // tiles per wave
#define WPB 4
#define TPB 256

// XOR bits[4:2] of the float index with bits[6:4]: bank-uniform b128 at both
// stride-4 (dense) and stride-16 (window) phases. Bijective within each
// 128 B block; slice base is 128B-aligned.
#define SWZ(s) ((s) ^ ((((s) >> 4) & 7) << 2))

// Compile-time ordering fence between LDS phases (no runtime instructions).
#define LDS_PHASE_FENCE() do { asm volatile("" ::: "memory"); \
                               __builtin_amdgcn_sched_barrier(0); } while (0)

__launch_bounds__(TPB, 4)
__global__ void filtfilt_kernel(const float* __restrict__ x,
                                const float* __restrict__ bco,
                                const float* __restrict__ aco,
                                float* __restrict__ out,
                                int rows) {
    __shared__ __align__(128) float xs_all[WPB][SLICE];   // 16,896 B
    const int tid = threadIdx.x;
    const int wid = tid >> 6;
    const int lane = tid & 63;
    float* __restrict__ xs = xs_all[wid];

    const int g = blockIdx.x * WPB + wid;      // global wave index
    const int row = g >> 2;                    // 4 waves per row
    const int segbase = (g & 3) * NITER;       // 8 consecutive segs per wave
    if (row >= rows) return;                   // wave-uniform

    const float inv_a0 = 1.0f / aco[0];
    const float B0 = bco[0] * inv_a0;
    const float B1 = bco[1] * inv_a0;
    const float B2 = bco[2] * inv_a0;
    const float A1 = aco[1] * inv_a0;
    const float A2 = aco[2] * inv_a0;

    const float* __restrict__ xrow = x + (size_t)row * N_COLS;
    float* __restrict__ orow0 = out + (size_t)row * N_COLS;

    // ---- register prefetch of one tile's slice (5 float4/lane, clamped;
    // the clamped/garbage elements are exactly the patched ones).
    float4 pf[5];
    auto issue = [&](int xoff) {
#pragma unroll
        for (int m = 0; m < 4; ++m) {
            int gg = xoff + 4 * (lane + LANES * m);
            gg = (gg < 0) ? 0 : gg;
            gg = (gg > N_COLS - 4) ? (N_COLS - 4) : gg;
            pf[m] = *(const float4*)(xrow + gg);
        }
        {   // tail: only 8 vec4 needed (NV4=264); lanes>=8 load duplicates
            int gg = xoff + 4 * (256 + (lane & 7));
            gg = (gg < 0) ? 0 : gg;
            gg = (gg > N_COLS - 4) ? (N_COLS - 4) : gg;
            pf[4] = *(const float4*)(xrow + gg);
        }
    };

    issue(segbase * P - WF);                   // prologue: tile 0 loads

    for (int it = 0; it < NITER; ++it) {
        const int seg = segbase + it;
        const int xoff = seg * P - WF;

        // ---- stage: 5 swizzled b128 LDS writes from prefetch regs
        // (compiler inserts the vmcnt wait for pf here).
#pragma unroll
        for (int m = 0; m < 4; ++m)
            *(float4*)(xs + SWZ(4 * (lane + LANES * m))) = pf[m];
        if (lane < 8)
            *(float4*)(xs + SWZ(4 * (256 + lane))) = pf[4];
        LDS_PHASE_FENCE();   // stage writes -> patch writes (cross-lane WAW)

        // ---- left patch (seg0): s in [0,16), t=s-7: zeros then odd-ext.
        if (seg == 0 && lane < WF) {
            const int t = lane - (WF - PAD);   // -7..8
            xs[SWZ(lane)] = (t < 0) ? 0.0f
                                    : (2.0f * xrow[0] - xrow[PAD - t]);
        }
        // ---- right patch (seg31): s in [1040,1056), t=32777+lane:
        // odd-ext for t<LTOT, zeros past (bwd carries z=0 to t=LTOT-1).
        if (seg == NSEG - 1 && lane < WF) {
            const int s = SLICE - WF + lane;
            xs[SWZ(s)] = (lane < PAD)
                       ? (2.0f * xrow[N_COLS - 1] - xrow[N_COLS - 2 - lane])
                       : 0.0f;
        }
        LDS_PHASE_FENCE();   // patch/stage writes -> window reads (RAW)

        // ---- prefetch next tile NOW: latency hides under window-read +
        // recurrence + copy-out of this tile.
        if (it < NITER - 1) issue(xoff + P);

        // ---- window read: 12 swizzled b128 (conflict-free) -> regs
        const int s0 = C * lane;
        float v[WIN];
#pragma unroll
        for (int j = 0; j < WIN / 4; ++j)
            *(float4*)(v + 4 * j) = *(const float4*)(xs + SWZ(s0 + 4 * j));

        // ---- forward biquad (z=0 at window start); keep y1 for k>=WF
        {
            float z0 = 0.0f, z1 = 0.0f;
#pragma unroll
            for (int k = 0; k < WIN; ++k) {
                const float xv = v[k];
                const float y = fmaf(B0, xv, z0);
                z0 = fmaf(-A1, y, fmaf(B1, xv, z1));
                z1 = fmaf(B2, xv, -A2 * y);
                if (k >= WF) v[k] = y;
            }
        }
        // ---- right edge: y1 at t>=LTOT reads as zero (lane63/seg31: t=32745+k)
        if (seg == NSEG - 1 && lane == LANES - 1) {
#pragma unroll
            for (int k = 41; k < WIN; ++k) v[k] = 0.0f;
        }
        // ---- backward: warmup on own y1 (k=47..32), outputs k=31..16
        {
            float z0 = 0.0f, z1 = 0.0f;
#pragma unroll
            for (int k = WIN - 1; k >= WF; --k) {
                const float xv = v[k];
                const float y = fmaf(B0, xv, z0);
                z0 = fmaf(-A1, y, fmaf(B1, xv, z1));
                z1 = fmaf(B2, xv, -A2 * y);
                if (k < WF + C) v[k] = y;
            }
        }
        LDS_PHASE_FENCE();   // window reads -> y2 writes (cross-lane WAR)

        // ---- y2 write in place: 4 swizzled b128
#pragma unroll
        for (int j = 0; j < C / 4; ++j)
            *(float4*)(xs + SWZ(s0 + WF + 4 * j)) = *(const float4*)(v + WF + 4 * j);
        LDS_PHASE_FENCE();   // y2 writes -> copy-out reads (cross-lane RAW)

        // ---- dense copy-out: 4 swizzled b128 reads -> 4 dense global stores
        float* __restrict__ orow = orow0 + seg * P;
#pragma unroll
        for (int m = 0; m < 4; ++m) {
            const int i = lane + LANES * m;
            *(float4*)(orow + 4 * i) = *(const float4*)(xs + SWZ(WF + 4 * i));
        }
        LDS_PHASE_FENCE();   // copy-out reads -> next iter's stage writes (WAR)
    }
}

extern "C" void kernel_launch(void* const* d_in, const int* in_sizes, int n_in,
                              void* d_out, int out_size, void* d_ws, size_t ws_size,
                              hipStream_t stream) {
    const float* x = (const float*)d_in[0];
    const float* b = (const float*)d_in[1];
    const float* a = (const float*)d_in[2];
    float* out = (float*)d_out;
    const int rows = out_size / N_COLS;                // 1024
    const int total_waves = rows * (NSEG / NITER);     // 4096
    const int blocks = (total_waves + WPB - 1) / WPB;  // 1024
    filtfilt_kernel<<<blocks, TPB, 0, stream>>>(x, b, a, out, rows);
}

// Round 7
// 241.099 us; speedup vs baseline: 1.0735x; 1.0735x over previous
//
#include <hip/hip_runtime.h>

// filtfilt (order-2 biquad, odd-ext pad=9) over 1024 rows x 32768 fp32.
//
// R10 = R9 (persistent pipelined waves, swizzled all-b128 LDS, lane-
// independent fwd/bwd) with the REGISTER SPILL fixed.
// R9's counters: WRITE_SIZE +149MB / FETCH +36MB vs ideal, VGPR_Count=60.
// Diagnosis: __launch_bounds__(256,4) sets only a MIN waves/EU; the
// allocator chased 8 waves/EU (<=64 VGPR) and spilled the pf[5] prefetch
// (80 B/lane/tile x 64 lanes x 4096 waves x 8 tiles ~ 167 MB scratch writes
// = the observed WRITE bloat; kernel = 394MB / 3.8TB/s = 104us). The grid
// is 4096 waves = 16/CU = 4/EU, so 8/EU bought nothing.
// Fix: amdgpu_waves_per_eu(4,4) pins the allocator at a 128-VGPR budget
// (no incentive to spill); prefetch held in five named float4 scalars.
// All staging/compute/patch logic identical to R9 (which passed).
// Warmup 16/16 (err 0.577^16 ~ 1.5e-4); edges exact.

#define N_COLS 32768
#define PAD 9
#define LTOT  (N_COLS + 2 * PAD)   // 32786
#define WF 16
#define WB 16
#define C  16                      // outputs per lane
#define LANES 64
#define P   (C * LANES)            // 1024 outputs per tile
#define NSEG (N_COLS / P)          // 32
#define WIN (WF + C + WB)          // 48 floats per lane
#define SLICE (WF + P + WB)        // 1056 floats = 128B-multiple
#define NITER 8                    // tiles per wave
#define WPB 4
#define TPB 256

// XOR bits[4:2] of the float index with bits[6:4]: bank-uniform b128 at both
// stride-4 (dense) and stride-16 (window) phases. Bijective within each
// 128 B block; slice base is 128B-aligned.
#define SWZ(s) ((s) ^ ((((s) >> 4) & 7) << 2))

// Compile-time ordering fence between LDS phases (no runtime instructions).
#define LDS_PHASE_FENCE() do { asm volatile("" ::: "memory"); \
                               __builtin_amdgcn_sched_barrier(0); } while (0)

#define CLAMP_IDX(g) ((g) < 0 ? 0 : ((g) > N_COLS - 4 ? N_COLS - 4 : (g)))

__attribute__((amdgpu_flat_work_group_size(TPB, TPB), amdgpu_waves_per_eu(4, 4)))
__global__ void filtfilt_kernel(const float* __restrict__ x,
                                const float* __restrict__ bco,
                                const float* __restrict__ aco,
                                float* __restrict__ out,
                                int rows) {
    __shared__ __align__(128) float xs_all[WPB][SLICE];   // 16,896 B
    const int tid = threadIdx.x;
    const int wid = tid >> 6;
    const int lane = tid & 63;
    float* __restrict__ xs = xs_all[wid];

    const int g = blockIdx.x * WPB + wid;      // global wave index
    const int row = g >> 2;                    // 4 waves per row
    const int segbase = (g & 3) * NITER;       // 8 consecutive segs per wave
    if (row >= rows) return;                   // wave-uniform

    const float inv_a0 = 1.0f / aco[0];
    const float B0 = bco[0] * inv_a0;
    const float B1 = bco[1] * inv_a0;
    const float B2 = bco[2] * inv_a0;
    const float A1 = aco[1] * inv_a0;
    const float A2 = aco[2] * inv_a0;

    const float* __restrict__ xrow = x + (size_t)row * N_COLS;
    float* __restrict__ orow0 = out + (size_t)row * N_COLS;

    // ---- register prefetch: five named float4 (no array -> SROA-trivial,
    // nothing for the allocator to spill as a unit). Clamped garbage lands
    // exactly on the patched elements.
    float4 pf0, pf1, pf2, pf3, pf4;
#define ISSUE(XOFF) do {                                                      \
        int g0_ = CLAMP_IDX((XOFF) + 4 * lane);                               \
        int g1_ = CLAMP_IDX((XOFF) + 4 * (lane + LANES));                     \
        int g2_ = CLAMP_IDX((XOFF) + 4 * (lane + 2 * LANES));                 \
        int g3_ = CLAMP_IDX((XOFF) + 4 * (lane + 3 * LANES));                 \
        int g4_ = CLAMP_IDX((XOFF) + 4 * (4 * LANES + (lane & 7)));           \
        pf0 = *(const float4*)(xrow + g0_);                                   \
        pf1 = *(const float4*)(xrow + g1_);                                   \
        pf2 = *(const float4*)(xrow + g2_);                                   \
        pf3 = *(const float4*)(xrow + g3_);                                   \
        pf4 = *(const float4*)(xrow + g4_);                                   \
    } while (0)

    ISSUE(segbase * P - WF);                   // prologue: tile 0 loads

    for (int it = 0; it < NITER; ++it) {
        const int seg = segbase + it;
        const int xoff = seg * P - WF;

        // ---- stage: 5 swizzled b128 LDS writes from prefetch regs
        // (compiler inserts the vmcnt wait here).
        *(float4*)(xs + SWZ(4 * lane))             = pf0;
        *(float4*)(xs + SWZ(4 * (lane + LANES)))   = pf1;
        *(float4*)(xs + SWZ(4 * (lane + 2*LANES))) = pf2;
        *(float4*)(xs + SWZ(4 * (lane + 3*LANES))) = pf3;
        if (lane < 8)
            *(float4*)(xs + SWZ(4 * (4*LANES + lane))) = pf4;
        LDS_PHASE_FENCE();   // stage writes -> patch writes (cross-lane WAW)

        // ---- left patch (seg0): s in [0,16), t=s-7: zeros then odd-ext.
        if (seg == 0 && lane < WF) {
            const int t = lane - (WF - PAD);   // -7..8
            xs[SWZ(lane)] = (t < 0) ? 0.0f
                                    : (2.0f * xrow[0] - xrow[PAD - t]);
        }
        // ---- right patch (seg31): s in [1040,1056), t=32777+lane:
        // odd-ext for t<LTOT, zeros past (bwd carries z=0 to t=LTOT-1).
        if (seg == NSEG - 1 && lane < WF) {
            const int s = SLICE - WF + lane;
            xs[SWZ(s)] = (lane < PAD)
                       ? (2.0f * xrow[N_COLS - 1] - xrow[N_COLS - 2 - lane])
                       : 0.0f;
        }
        LDS_PHASE_FENCE();   // patch/stage writes -> window reads (RAW)

        // ---- prefetch next tile NOW: latency hides under window-read +
        // recurrence + copy-out of this tile.
        if (it < NITER - 1) ISSUE(xoff + P);

        // ---- window read: 12 swizzled b128 (conflict-free) -> regs
        const int s0 = C * lane;
        float v[WIN];
#pragma unroll
        for (int j = 0; j < WIN / 4; ++j)
            *(float4*)(v + 4 * j) = *(const float4*)(xs + SWZ(s0 + 4 * j));

        // ---- forward biquad (z=0 at window start); keep y1 for k>=WF
        {
            float z0 = 0.0f, z1 = 0.0f;
#pragma unroll
            for (int k = 0; k < WIN; ++k) {
                const float xv = v[k];
                const float y = fmaf(B0, xv, z0);
                z0 = fmaf(-A1, y, fmaf(B1, xv, z1));
                z1 = fmaf(B2, xv, -A2 * y);
                if (k >= WF) v[k] = y;
            }
        }
        // ---- right edge: y1 at t>=LTOT reads as zero (lane63/seg31: t=32745+k)
        if (seg == NSEG - 1 && lane == LANES - 1) {
#pragma unroll
            for (int k = 41; k < WIN; ++k) v[k] = 0.0f;
        }
        // ---- backward: warmup on own y1 (k=47..32), outputs k=31..16
        {
            float z0 = 0.0f, z1 = 0.0f;
#pragma unroll
            for (int k = WIN - 1; k >= WF; --k) {
                const float xv = v[k];
                const float y = fmaf(B0, xv, z0);
                z0 = fmaf(-A1, y, fmaf(B1, xv, z1));
                z1 = fmaf(B2, xv, -A2 * y);
                if (k < WF + C) v[k] = y;
            }
        }
        LDS_PHASE_FENCE();   // window reads -> y2 writes (cross-lane WAR)

        // ---- y2 write in place: 4 swizzled b128
#pragma unroll
        for (int j = 0; j < C / 4; ++j)
            *(float4*)(xs + SWZ(s0 + WF + 4 * j)) = *(const float4*)(v + WF + 4 * j);
        LDS_PHASE_FENCE();   // y2 writes -> copy-out reads (cross-lane RAW)

        // ---- dense copy-out: 4 swizzled b128 reads -> 4 dense global stores
        float* __restrict__ orow = orow0 + seg * P;
#pragma unroll
        for (int m = 0; m < 4; ++m) {
            const int i = lane + LANES * m;
            *(float4*)(orow + 4 * i) = *(const float4*)(xs + SWZ(WF + 4 * i));
        }
        LDS_PHASE_FENCE();   // copy-out reads -> next iter's stage writes (WAR)
    }
#undef ISSUE
}

extern "C" void kernel_launch(void* const* d_in, const int* in_sizes, int n_in,
                              void* d_out, int out_size, void* d_ws, size_t ws_size,
                              hipStream_t stream) {
    const float* x = (const float*)d_in[0];
    const float* b = (const float*)d_in[1];
    const float* a = (const float*)d_in[2];
    float* out = (float*)d_out;
    const int rows = out_size / N_COLS;                // 1024
    const int total_waves = rows * (NSEG / NITER);     // 4096
    const int blocks = (total_waves + WPB - 1) / WPB;  // 1024
    filtfilt_kernel<<<blocks, TPB, 0, stream>>>(x, b, a, out, rows);
}